// Round 3
// baseline (806.566 us; speedup 1.0000x reference)
//
#include <hip/hip_runtime.h>
#include <hip/hip_bf16.h>
#include <stdint.h>

#define T_TOK 2048
#define H_DIM 2048
#define E_NUM 16
#define I_DIM 768

typedef __bf16 bf16;
typedef __bf16 bf16x4 __attribute__((ext_vector_type(4)));
typedef __bf16 bf16x8 __attribute__((ext_vector_type(8)));
typedef float f32x4 __attribute__((ext_vector_type(4)));

// ---------------- Router: fp64 logits, shuffle reduce, top-2, x->bf16 --------
__global__ __launch_bounds__(256) void router_kernel(
    const float* __restrict__ x, const float* __restrict__ gw,
    float* __restrict__ logits, int* __restrict__ cnt,
    int* __restrict__ tok_list, float* __restrict__ wgt_list,
    bf16* __restrict__ xb)
{
    const int t = blockIdx.x;
    const int tid = threadIdx.x;
    const int lane = tid & 63, wid = tid >> 6;

    double part[E_NUM];
#pragma unroll
    for (int e = 0; e < E_NUM; ++e) part[e] = 0.0;

#pragma unroll
    for (int it = 0; it < 2; ++it) {
        int h = it * 1024 + tid * 4;
        float4 xv = *(const float4*)(x + (size_t)t * H_DIM + h);
        bf16x4 xb4 = { (bf16)xv.x, (bf16)xv.y, (bf16)xv.z, (bf16)xv.w };
        *(bf16x4*)(xb + (size_t)t * H_DIM + h) = xb4;
#pragma unroll
        for (int e = 0; e < E_NUM; ++e) {
            float4 wv = *(const float4*)(gw + (size_t)e * H_DIM + h);
            part[e] += (double)xv.x * (double)wv.x + (double)xv.y * (double)wv.y
                     + (double)xv.z * (double)wv.z + (double)xv.w * (double)wv.w;
        }
    }
    // wave-level butterfly
#pragma unroll
    for (int off = 32; off > 0; off >>= 1)
#pragma unroll
        for (int e = 0; e < E_NUM; ++e)
            part[e] += __shfl_down(part[e], off);

    __shared__ double sh[4][E_NUM];
    __shared__ float lg[E_NUM];
    if (lane == 0)
#pragma unroll
        for (int e = 0; e < E_NUM; ++e) sh[wid][e] = part[e];
    __syncthreads();
    if (tid < E_NUM) {
        float v = (float)(sh[0][tid] + sh[1][tid] + sh[2][tid] + sh[3][tid]);
        lg[tid] = v;
        logits[(size_t)t * E_NUM + tid] = v;
    }
    __syncthreads();
    if (tid == 0) {
        int i0 = 0; float v0 = lg[0];
#pragma unroll
        for (int e = 1; e < E_NUM; ++e) if (lg[e] > v0) { v0 = lg[e]; i0 = e; }
        int i1 = -1; float v1 = -3.4e38f;
#pragma unroll
        for (int e = 0; e < E_NUM; ++e) if (e != i0 && lg[e] > v1) { v1 = lg[e]; i1 = e; }
        float w0 = 1.0f / (1.0f + __expf(v1 - v0));
        float w1 = 1.0f - w0;
        int p0 = atomicAdd(&cnt[i0], 1);
        tok_list[i0 * T_TOK + p0] = t; wgt_list[i0 * T_TOK + p0] = w0;
        int p1 = atomicAdd(&cnt[i1], 1);
        tok_list[i1 * T_TOK + p1] = t; wgt_list[i1 * T_TOK + p1] = w1;
    }
}

// ---------------- Offsets scan (16 values) ----------------------------------
__global__ void scan_kernel(const int* __restrict__ cnt, int* __restrict__ offs)
{
    if (threadIdx.x == 0) {
        int o = 0;
        for (int e = 0; e < E_NUM; ++e) { offs[e] = o; o += cnt[e]; }
    }
}

// ---------------- Grouped gate_up GEMM + SwiGLU ------------------------------
// Streaming flatmm: NO LDS, NO barriers. A (bf16 tokens) and B (fp32 weights)
// load direct global->register, depth-1 register double-buffer. Weights have
// zero reuse, so LDS staging only added barrier latency; L1/L2 covers the
// 2-wave intra-block sharing. Per wave: 32 tok x 64 i-cols output.
__global__ __launch_bounds__(256, 2) void gateup_kernel(
    const bf16* __restrict__ xb, const float* __restrict__ gup,
    const int* __restrict__ cnt, const int* __restrict__ offs,
    const int* __restrict__ tok_list, bf16* __restrict__ hbuf)
{
    const int e = blockIdx.z;
    const int count = cnt[e];
    const int row0 = blockIdx.y * 64;
    if (row0 >= count) return;
    const int i0 = blockIdx.x * 64;
    const int hoff = offs[e];
    const int tid = threadIdx.x;
    const int lane = tid & 63, wid = tid >> 6;
    const int la = lane & 15, lq = lane >> 4;
    const int wm = wid >> 1, wn = wid & 1;

    // A fragment bases: lane la picks token row, lq picks 16B k-chunk.
    const bf16* srcA[2];
#pragma unroll
    for (int mt = 0; mt < 2; ++mt) {
        int tr = row0 + 32 * wm + 16 * mt + la;
        if (tr >= count) tr = count - 1;
        srcA[mt] = xb + (size_t)tok_list[e * T_TOK + tr] * H_DIM + lq * 8;
    }
    // B fragment bases: lane la picks weight row (16 rows per nt), lq k-chunk.
    // nt 0,1 = gate cols i0+32wn+{0,16}+la ; nt 2,3 = up same cols.
    const float* srcB[4];
#pragma unroll
    for (int nt = 0; nt < 4; ++nt) {
        size_t grow = (size_t)e * (2 * I_DIM) + (size_t)(nt >> 1) * I_DIM
                    + i0 + 32 * wn + 16 * (nt & 1) + la;
        srcB[nt] = gup + grow * H_DIM + lq * 8;
    }

    f32x4 acc[2][4];
#pragma unroll
    for (int a = 0; a < 2; ++a)
#pragma unroll
        for (int b = 0; b < 4; ++b) acc[a][b] = (f32x4){0.f, 0.f, 0.f, 0.f};

    f32x4 vb0[4][4], vb1[4][4];     // [nt][ks*2+half] fp32 weight frags
    bf16x8 va0[2][2], va1[2][2];    // [mt][ks] token frags

    auto loadT = [&](f32x4 (&vb)[4][4], bf16x8 (&va)[2][2], int k0) {
#pragma unroll
        for (int nt = 0; nt < 4; ++nt)
#pragma unroll
            for (int ks = 0; ks < 2; ++ks) {
                vb[nt][ks * 2]     = *(const f32x4*)(srcB[nt] + k0 + ks * 32);
                vb[nt][ks * 2 + 1] = *(const f32x4*)(srcB[nt] + k0 + ks * 32 + 4);
            }
#pragma unroll
        for (int mt = 0; mt < 2; ++mt)
#pragma unroll
            for (int ks = 0; ks < 2; ++ks)
                va[mt][ks] = *(const bf16x8*)(srcA[mt] + k0 + ks * 32);
    };
    auto computeT = [&](const f32x4 (&vb)[4][4], const bf16x8 (&va)[2][2]) {
#pragma unroll
        for (int ks = 0; ks < 2; ++ks) {
            bf16x8 bfr[4];
#pragma unroll
            for (int nt = 0; nt < 4; ++nt) {
                const f32x4 v0 = vb[nt][ks * 2], v1 = vb[nt][ks * 2 + 1];
                bfr[nt] = (bf16x8){ (bf16)v0.x, (bf16)v0.y, (bf16)v0.z, (bf16)v0.w,
                                    (bf16)v1.x, (bf16)v1.y, (bf16)v1.z, (bf16)v1.w };
            }
#pragma unroll
            for (int mt = 0; mt < 2; ++mt)
#pragma unroll
                for (int nt = 0; nt < 4; ++nt)
                    acc[mt][nt] = __builtin_amdgcn_mfma_f32_16x16x32_bf16(
                        va[mt][ks], bfr[nt], acc[mt][nt], 0, 0, 0);
        }
    };

    const int NK = H_DIM / 64;      // 32, even
    loadT(vb0, va0, 0);
    for (int kt = 0; kt < NK; kt += 2) {
        loadT(vb1, va1, (kt + 1) * 64);           // kt+1 < NK always (NK even)
        computeT(vb0, va0);
        if (kt + 2 < NK) loadT(vb0, va0, (kt + 2) * 64);
        computeT(vb1, va1);
    }

    // epilogue: nt {0,1} = g, nt {2,3} = u for the same i-range
#pragma unroll
    for (int mt = 0; mt < 2; ++mt)
#pragma unroll
        for (int p = 0; p < 2; ++p)
#pragma unroll
            for (int r = 0; r < 4; ++r) {
                int trow = 32 * wm + 16 * mt + lq * 4 + r;
                if (row0 + trow < count) {
                    float g = acc[mt][p][r], u = acc[mt][p + 2][r];
                    float hv = (g / (1.0f + __expf(-g))) * u;
                    int col = i0 + 32 * wn + 16 * p + la;
                    hbuf[(size_t)(hoff + row0 + trow) * I_DIM + col] = (bf16)hv;
                }
            }
}

// ---------------- Grouped down GEMM + weighted scatter -----------------------
// Same streaming flatmm structure. M=64 tok x N=128 H-cols, K=768.
__global__ __launch_bounds__(256, 2) void down_kernel(
    const float* __restrict__ dw, const bf16* __restrict__ hbuf,
    const int* __restrict__ cnt, const int* __restrict__ offs,
    const int* __restrict__ tok_list, const float* __restrict__ wgt_list,
    float* __restrict__ out)
{
    const int e = blockIdx.z;
    const int count = cnt[e];
    const int row0 = blockIdx.y * 64;
    if (row0 >= count) return;
    const int n0 = blockIdx.x * 128;
    const int hoff = offs[e];
    const int tid = threadIdx.x;
    const int lane = tid & 63, wid = tid >> 6;
    const int la = lane & 15, lq = lane >> 4;
    const int wm = wid >> 1, wn = wid & 1;

    const bf16* srcA[2];
#pragma unroll
    for (int mt = 0; mt < 2; ++mt) {
        int tr = row0 + 32 * wm + 16 * mt + la;
        if (tr >= count) tr = count - 1;
        srcA[mt] = hbuf + (size_t)(hoff + tr) * I_DIM + lq * 8;
    }
    const float* srcB[4];
#pragma unroll
    for (int nt = 0; nt < 4; ++nt) {
        size_t grow = (size_t)e * H_DIM + n0 + 64 * wn + 16 * nt + la;
        srcB[nt] = dw + grow * I_DIM + lq * 8;
    }

    f32x4 acc[2][4];
#pragma unroll
    for (int a = 0; a < 2; ++a)
#pragma unroll
        for (int b = 0; b < 4; ++b) acc[a][b] = (f32x4){0.f, 0.f, 0.f, 0.f};

    f32x4 vb0[4][4], vb1[4][4];
    bf16x8 va0[2][2], va1[2][2];

    auto loadT = [&](f32x4 (&vb)[4][4], bf16x8 (&va)[2][2], int k0) {
#pragma unroll
        for (int nt = 0; nt < 4; ++nt)
#pragma unroll
            for (int ks = 0; ks < 2; ++ks) {
                vb[nt][ks * 2]     = *(const f32x4*)(srcB[nt] + k0 + ks * 32);
                vb[nt][ks * 2 + 1] = *(const f32x4*)(srcB[nt] + k0 + ks * 32 + 4);
            }
#pragma unroll
        for (int mt = 0; mt < 2; ++mt)
#pragma unroll
            for (int ks = 0; ks < 2; ++ks)
                va[mt][ks] = *(const bf16x8*)(srcA[mt] + k0 + ks * 32);
    };
    auto computeT = [&](const f32x4 (&vb)[4][4], const bf16x8 (&va)[2][2]) {
#pragma unroll
        for (int ks = 0; ks < 2; ++ks) {
            bf16x8 bfr[4];
#pragma unroll
            for (int nt = 0; nt < 4; ++nt) {
                const f32x4 v0 = vb[nt][ks * 2], v1 = vb[nt][ks * 2 + 1];
                bfr[nt] = (bf16x8){ (bf16)v0.x, (bf16)v0.y, (bf16)v0.z, (bf16)v0.w,
                                    (bf16)v1.x, (bf16)v1.y, (bf16)v1.z, (bf16)v1.w };
            }
#pragma unroll
            for (int mt = 0; mt < 2; ++mt)
#pragma unroll
                for (int nt = 0; nt < 4; ++nt)
                    acc[mt][nt] = __builtin_amdgcn_mfma_f32_16x16x32_bf16(
                        va[mt][ks], bfr[nt], acc[mt][nt], 0, 0, 0);
        }
    };

    const int NK = I_DIM / 64;      // 12, even
    loadT(vb0, va0, 0);
    for (int kt = 0; kt < NK; kt += 2) {
        loadT(vb1, va1, (kt + 1) * 64);
        computeT(vb0, va0);
        if (kt + 2 < NK) loadT(vb0, va0, (kt + 2) * 64);
        computeT(vb1, va1);
    }

#pragma unroll
    for (int mt = 0; mt < 2; ++mt)
#pragma unroll
        for (int nt = 0; nt < 4; ++nt)
#pragma unroll
            for (int r = 0; r < 4; ++r) {
                int trow = 32 * wm + 16 * mt + lq * 4 + r;
                if (row0 + trow < count) {
                    int col = n0 + 64 * wn + 16 * nt + la;
                    int grow = row0 + trow;
                    atomicAdd(&out[(size_t)tok_list[e * T_TOK + grow] * H_DIM + col],
                              wgt_list[e * T_TOK + grow] * acc[mt][nt][r]);
                }
            }
}

// ---------------- Launch -----------------------------------------------------
extern "C" void kernel_launch(void* const* d_in, const int* in_sizes, int n_in,
                              void* d_out, int out_size, void* d_ws, size_t ws_size,
                              hipStream_t stream)
{
    const float* x   = (const float*)d_in[0];
    const float* gw  = (const float*)d_in[1];
    const float* gup = (const float*)d_in[2];
    const float* dw  = (const float*)d_in[3];
    float* out = (float*)d_out;
    float* logits = out + (size_t)T_TOK * H_DIM;

    char* ws = (char*)d_ws;
    int*   cnt      = (int*)(ws + 0);
    int*   offs     = (int*)(ws + 256);
    int*   tok_list = (int*)(ws + 512);                 // 128 KiB
    float* wgt_list = (float*)(ws + 131584);            // 128 KiB
    bf16*  hbuf     = (bf16*)(ws + 262656);             // 6 MiB
    bf16*  xb       = (bf16*)(ws + 6554112);            // 8 MiB (end ~14.3 MiB)

    hipMemsetAsync(cnt, 0, 256, stream);
    hipMemsetAsync(out, 0, (size_t)T_TOK * H_DIM * sizeof(float), stream);

    router_kernel<<<T_TOK, 256, 0, stream>>>(x, gw, logits, cnt, tok_list, wgt_list, xb);
    scan_kernel<<<1, 64, 0, stream>>>(cnt, offs);
    gateup_kernel<<<dim3(I_DIM / 64, T_TOK / 64, E_NUM), 256, 0, stream>>>(
        xb, gup, cnt, offs, tok_list, hbuf);
    down_kernel<<<dim3(H_DIM / 128, T_TOK / 64, E_NUM), 256, 0, stream>>>(
        dw, hbuf, cnt, offs, tok_list, wgt_list, out);
}

// Round 4
// 715.273 us; speedup vs baseline: 1.1276x; 1.1276x over previous
//
#include <hip/hip_runtime.h>
#include <hip/hip_bf16.h>
#include <stdint.h>

#define T_TOK 2048
#define H_DIM 2048
#define E_NUM 16
#define I_DIM 768

typedef __bf16 bf16;
typedef __bf16 bf16x4 __attribute__((ext_vector_type(4)));
typedef __bf16 bf16x8 __attribute__((ext_vector_type(8)));
typedef float f32x4 __attribute__((ext_vector_type(4)));

__device__ __forceinline__ void async_cp16(void* l, const void* g) {
    __builtin_amdgcn_global_load_lds(
        (const __attribute__((address_space(1))) void*)g,
        (__attribute__((address_space(3))) void*)l, 16, 0, 0);
}

// ---------------- Router: fp64 logits, shuffle reduce, top-2, x->bf16 --------
__global__ __launch_bounds__(256) void router_kernel(
    const float* __restrict__ x, const float* __restrict__ gw,
    float* __restrict__ logits, int* __restrict__ cnt,
    int* __restrict__ tok_list, float* __restrict__ wgt_list,
    bf16* __restrict__ xb)
{
    const int t = blockIdx.x;
    const int tid = threadIdx.x;
    const int lane = tid & 63, wid = tid >> 6;

    double part[E_NUM];
#pragma unroll
    for (int e = 0; e < E_NUM; ++e) part[e] = 0.0;

#pragma unroll
    for (int it = 0; it < 2; ++it) {
        int h = it * 1024 + tid * 4;
        float4 xv = *(const float4*)(x + (size_t)t * H_DIM + h);
        bf16x4 xb4 = { (bf16)xv.x, (bf16)xv.y, (bf16)xv.z, (bf16)xv.w };
        *(bf16x4*)(xb + (size_t)t * H_DIM + h) = xb4;
#pragma unroll
        for (int e = 0; e < E_NUM; ++e) {
            float4 wv = *(const float4*)(gw + (size_t)e * H_DIM + h);
            part[e] += (double)xv.x * (double)wv.x + (double)xv.y * (double)wv.y
                     + (double)xv.z * (double)wv.z + (double)xv.w * (double)wv.w;
        }
    }
    // wave-level butterfly
#pragma unroll
    for (int off = 32; off > 0; off >>= 1)
#pragma unroll
        for (int e = 0; e < E_NUM; ++e)
            part[e] += __shfl_down(part[e], off);

    __shared__ double sh[4][E_NUM];
    __shared__ float lg[E_NUM];
    if (lane == 0)
#pragma unroll
        for (int e = 0; e < E_NUM; ++e) sh[wid][e] = part[e];
    __syncthreads();
    if (tid < E_NUM) {
        float v = (float)(sh[0][tid] + sh[1][tid] + sh[2][tid] + sh[3][tid]);
        lg[tid] = v;
        logits[(size_t)t * E_NUM + tid] = v;
    }
    __syncthreads();
    if (tid == 0) {
        int i0 = 0; float v0 = lg[0];
#pragma unroll
        for (int e = 1; e < E_NUM; ++e) if (lg[e] > v0) { v0 = lg[e]; i0 = e; }
        int i1 = -1; float v1 = -3.4e38f;
#pragma unroll
        for (int e = 0; e < E_NUM; ++e) if (e != i0 && lg[e] > v1) { v1 = lg[e]; i1 = e; }
        float w0 = 1.0f / (1.0f + __expf(v1 - v0));
        float w1 = 1.0f - w0;
        int p0 = atomicAdd(&cnt[i0], 1);
        tok_list[i0 * T_TOK + p0] = t; wgt_list[i0 * T_TOK + p0] = w0;
        int p1 = atomicAdd(&cnt[i1], 1);
        tok_list[i1 * T_TOK + p1] = t; wgt_list[i1 * T_TOK + p1] = w1;
    }
}

// ---------------- Offsets scan (16 values) ----------------------------------
__global__ void scan_kernel(const int* __restrict__ cnt, int* __restrict__ offs)
{
    if (threadIdx.x == 0) {
        int o = 0;
        for (int e = 0; e < E_NUM; ++e) { offs[e] = o; o += cnt[e]; }
    }
}

// ---------------- Grouped gate_up GEMM + SwiGLU ------------------------------
// K-outer / M-in-register: block = (expert, 64 i-cols), owns up to 512 tokens.
// B panel (128 rows x 2048 K) streamed from HBM EXACTLY ONCE per block,
// staged coalesced via global_load_lds (XOR swizzle), double-buffered.
// 8 waves x 64-token chunk; acc 128 VGPR/thread; A-frags direct from global
// (full 64B-line use per 4 lanes). 64 MFMA per wave per barrier.
__global__ __launch_bounds__(512, 2) void gateup_kernel(
    const bf16* __restrict__ xb, const float* __restrict__ gup,
    const int* __restrict__ cnt, const int* __restrict__ offs,
    const int* __restrict__ tok_list, bf16* __restrict__ hbuf)
{
    const int e = blockIdx.z;
    const int count = cnt[e];
    const int rbase = blockIdx.y * 512;
    if (rbase >= count) return;
    const int i0 = blockIdx.x * 64;
    const int hoff = offs[e];
    const int tid = threadIdx.x;
    const int lane = tid & 63, wid = tid >> 6;
    const int la = lane & 15, lq = lane >> 4;

    __shared__ __align__(16) float Bs[2][128 * 64];   // 2 x 32 KB

    // ---- B staging: 128 rows (r<64: gate, r>=64: up) x 16 f32x4 chunks,
    //      slot s holds global chunk c = s ^ (r&15). 4 chunks/thread.
    const float* srcB[4]; int dstB[4];
#pragma unroll
    for (int i = 0; i < 4; ++i) {
        int idx = i * 512 + tid;
        int r = idx >> 4, s = idx & 15;
        int c = s ^ (r & 15);
        size_t grow = (size_t)e * (2 * I_DIM) + (size_t)(r >> 6) * I_DIM + i0 + (r & 63);
        srcB[i] = gup + grow * H_DIM + c * 4;
        dstB[i] = idx * 4;              // f32 element offset (16B chunks, linear)
    }

    // ---- A fragment pointers: wave wid owns tokens [rbase+wid*64, +64)
    const bool active = (rbase + wid * 64) < count;
    const bf16* pA[4];
#pragma unroll
    for (int mt = 0; mt < 4; ++mt) {
        int row = rbase + wid * 64 + mt * 16 + la;
        if (row >= count) row = count - 1;
        pA[mt] = xb + (size_t)tok_list[e * T_TOK + row] * H_DIM + lq * 8;
    }

    f32x4 acc[4][8];
#pragma unroll
    for (int a = 0; a < 4; ++a)
#pragma unroll
        for (int b = 0; b < 8; ++b) acc[a][b] = (f32x4){0.f, 0.f, 0.f, 0.f};

    bf16x8 af0[4][2], af1[4][2];

    auto stage = [&](int buf, int kt) {
#pragma unroll
        for (int i = 0; i < 4; ++i)
            async_cp16(&Bs[buf][dstB[i]], srcB[i] + kt * 64);
    };
    auto loadA = [&](bf16x8 (&af)[4][2], int kt) {
#pragma unroll
        for (int mt = 0; mt < 4; ++mt)
#pragma unroll
            for (int ks = 0; ks < 2; ++ks)
                af[mt][ks] = *(const bf16x8*)(pA[mt] + kt * 64 + ks * 32);
    };
    auto compute = [&](const float* Bsc, const bf16x8 (&af)[4][2]) {
#pragma unroll
        for (int ks = 0; ks < 2; ++ks)
#pragma unroll
            for (int nt = 0; nt < 8; ++nt) {
                int row = nt * 16 + la;
                int s0 = (ks * 8 + lq * 2) ^ (row & 15);
                f32x4 v0 = *(const f32x4*)(Bsc + (size_t)(row * 16 + s0) * 4);
                f32x4 v1 = *(const f32x4*)(Bsc + (size_t)(row * 16 + (s0 ^ 1)) * 4);
                bf16x8 b = { (bf16)v0.x, (bf16)v0.y, (bf16)v0.z, (bf16)v0.w,
                             (bf16)v1.x, (bf16)v1.y, (bf16)v1.z, (bf16)v1.w };
#pragma unroll
                for (int mt = 0; mt < 4; ++mt)
                    acc[mt][nt] = __builtin_amdgcn_mfma_f32_16x16x32_bf16(
                        af[mt][ks], b, acc[mt][nt], 0, 0, 0);
            }
    };

    const int NK = H_DIM / 64;          // 32, even
    stage(0, 0);
    if (active) loadA(af0, 0);
    __syncthreads();
    for (int kt = 0; kt < NK; kt += 2) {
        stage(1, kt + 1);                           // kt+1 < NK (NK even)
        if (active) { loadA(af1, kt + 1); compute(Bs[0], af0); }
        __syncthreads();
        if (kt + 2 < NK) {
            stage(0, kt + 2);
            if (active) loadA(af0, kt + 2);
        }
        if (active) compute(Bs[1], af1);
        __syncthreads();
    }

    // ---- epilogue: nt 0-3 = gate tiles, nt 4-7 = up tiles (same i-cols)
    if (active) {
#pragma unroll
        for (int mt = 0; mt < 4; ++mt)
#pragma unroll
            for (int p = 0; p < 4; ++p)
#pragma unroll
                for (int r = 0; r < 4; ++r) {
                    int row = rbase + wid * 64 + mt * 16 + lq * 4 + r;
                    if (row < count) {
                        float g = acc[mt][p][r], u = acc[mt][p + 4][r];
                        float hv = (g / (1.0f + __expf(-g))) * u;
                        hbuf[(size_t)(hoff + row) * I_DIM + i0 + p * 16 + la] = (bf16)hv;
                    }
                }
    }
}

// ---------------- Grouped down GEMM + weighted scatter -----------------------
// Same K-outer / M-in-register structure. Block = (expert, 128 H-cols),
// owns up to 512 tokens; dw panel (128 x 768) streamed once. K = 768.
__global__ __launch_bounds__(512, 2) void down_kernel(
    const float* __restrict__ dw, const bf16* __restrict__ hbuf,
    const int* __restrict__ cnt, const int* __restrict__ offs,
    const int* __restrict__ tok_list, const float* __restrict__ wgt_list,
    float* __restrict__ out)
{
    const int e = blockIdx.z;
    const int count = cnt[e];
    const int rbase = blockIdx.y * 512;
    if (rbase >= count) return;
    const int n0 = blockIdx.x * 128;
    const int hoff = offs[e];
    const int tid = threadIdx.x;
    const int lane = tid & 63, wid = tid >> 6;
    const int la = lane & 15, lq = lane >> 4;

    __shared__ __align__(16) float Bs[2][128 * 64];   // 2 x 32 KB

    const float* srcB[4]; int dstB[4];
#pragma unroll
    for (int i = 0; i < 4; ++i) {
        int idx = i * 512 + tid;
        int r = idx >> 4, s = idx & 15;
        int c = s ^ (r & 15);
        srcB[i] = dw + ((size_t)e * H_DIM + n0 + r) * I_DIM + c * 4;
        dstB[i] = idx * 4;
    }

    const bool active = (rbase + wid * 64) < count;
    const bf16* pA[4];
#pragma unroll
    for (int mt = 0; mt < 4; ++mt) {
        int row = rbase + wid * 64 + mt * 16 + la;
        if (row >= count) row = count - 1;
        pA[mt] = hbuf + (size_t)(hoff + row) * I_DIM + lq * 8;
    }

    f32x4 acc[4][8];
#pragma unroll
    for (int a = 0; a < 4; ++a)
#pragma unroll
        for (int b = 0; b < 8; ++b) acc[a][b] = (f32x4){0.f, 0.f, 0.f, 0.f};

    bf16x8 af0[4][2], af1[4][2];

    auto stage = [&](int buf, int kt) {
#pragma unroll
        for (int i = 0; i < 4; ++i)
            async_cp16(&Bs[buf][dstB[i]], srcB[i] + kt * 64);
    };
    auto loadA = [&](bf16x8 (&af)[4][2], int kt) {
#pragma unroll
        for (int mt = 0; mt < 4; ++mt)
#pragma unroll
            for (int ks = 0; ks < 2; ++ks)
                af[mt][ks] = *(const bf16x8*)(pA[mt] + kt * 64 + ks * 32);
    };
    auto compute = [&](const float* Bsc, const bf16x8 (&af)[4][2]) {
#pragma unroll
        for (int ks = 0; ks < 2; ++ks)
#pragma unroll
            for (int nt = 0; nt < 8; ++nt) {
                int row = nt * 16 + la;
                int s0 = (ks * 8 + lq * 2) ^ (row & 15);
                f32x4 v0 = *(const f32x4*)(Bsc + (size_t)(row * 16 + s0) * 4);
                f32x4 v1 = *(const f32x4*)(Bsc + (size_t)(row * 16 + (s0 ^ 1)) * 4);
                bf16x8 b = { (bf16)v0.x, (bf16)v0.y, (bf16)v0.z, (bf16)v0.w,
                             (bf16)v1.x, (bf16)v1.y, (bf16)v1.z, (bf16)v1.w };
#pragma unroll
                for (int mt = 0; mt < 4; ++mt)
                    acc[mt][nt] = __builtin_amdgcn_mfma_f32_16x16x32_bf16(
                        af[mt][ks], b, acc[mt][nt], 0, 0, 0);
            }
    };

    const int NK = I_DIM / 64;          // 12, even
    stage(0, 0);
    if (active) loadA(af0, 0);
    __syncthreads();
    for (int kt = 0; kt < NK; kt += 2) {
        stage(1, kt + 1);
        if (active) { loadA(af1, kt + 1); compute(Bs[0], af0); }
        __syncthreads();
        if (kt + 2 < NK) {
            stage(0, kt + 2);
            if (active) loadA(af0, kt + 2);
        }
        if (active) compute(Bs[1], af1);
        __syncthreads();
    }

    if (active) {
#pragma unroll
        for (int mt = 0; mt < 4; ++mt)
#pragma unroll
            for (int nt = 0; nt < 8; ++nt)
#pragma unroll
                for (int r = 0; r < 4; ++r) {
                    int row = rbase + wid * 64 + mt * 16 + lq * 4 + r;
                    if (row < count) {
                        int col = n0 + nt * 16 + la;
                        atomicAdd(&out[(size_t)tok_list[e * T_TOK + row] * H_DIM + col],
                                  wgt_list[e * T_TOK + row] * acc[mt][nt][r]);
                    }
                }
    }
}

// ---------------- Launch -----------------------------------------------------
extern "C" void kernel_launch(void* const* d_in, const int* in_sizes, int n_in,
                              void* d_out, int out_size, void* d_ws, size_t ws_size,
                              hipStream_t stream)
{
    const float* x   = (const float*)d_in[0];
    const float* gw  = (const float*)d_in[1];
    const float* gup = (const float*)d_in[2];
    const float* dw  = (const float*)d_in[3];
    float* out = (float*)d_out;
    float* logits = out + (size_t)T_TOK * H_DIM;

    char* ws = (char*)d_ws;
    int*   cnt      = (int*)(ws + 0);
    int*   offs     = (int*)(ws + 256);
    int*   tok_list = (int*)(ws + 512);                 // 128 KiB
    float* wgt_list = (float*)(ws + 131584);            // 128 KiB
    bf16*  hbuf     = (bf16*)(ws + 262656);             // 6 MiB
    bf16*  xb       = (bf16*)(ws + 6554112);            // 8 MiB (end ~14.3 MiB)

    hipMemsetAsync(cnt, 0, 256, stream);
    hipMemsetAsync(out, 0, (size_t)T_TOK * H_DIM * sizeof(float), stream);

    router_kernel<<<T_TOK, 256, 0, stream>>>(x, gw, logits, cnt, tok_list, wgt_list, xb);
    scan_kernel<<<1, 64, 0, stream>>>(cnt, offs);
    // y covers up to 2048 tokens/expert for pathological routing; ghost blocks
    // (rbase >= count) exit immediately. Typical count≈256 -> y=0 only.
    gateup_kernel<<<dim3(I_DIM / 64, 4, E_NUM), 512, 0, stream>>>(
        xb, gup, cnt, offs, tok_list, hbuf);
    down_kernel<<<dim3(H_DIM / 128, 4, E_NUM), 512, 0, stream>>>(
        dw, hbuf, cnt, offs, tok_list, wgt_list, out);
}